// Round 2
// baseline (660.015 us; speedup 1.0000x reference)
//
#include <hip/hip_runtime.h>
#include <math.h>

#define BSZ 4096
#define NV 2
#define DIM 128
#define NTOT (BSZ * NV)     // 8192
#define BM 32
#define BN 128
#define NTHR 256

constexpr float TEMP  = 0.07f;
constexpr float INV_T = 1.0f / TEMP;   // also the fixed softmax shift M0 (cos <= 1)
constexpr float M0    = INV_T;

// ---------------- kernel 1: inverse norms ----------------
// invnorm[i] = 1/sqrt(sum_d feat[b,v,d]^2 + 1e-12), i = v*BSZ + b (view-major stacking)
__global__ void norm_kernel(const float* __restrict__ feat, float* __restrict__ invnorm) {
    const int i = blockIdx.x;
    const int b = i & (BSZ - 1);
    const int v = i >> 12;            // i / BSZ
    const float2 x = reinterpret_cast<const float2*>(feat + (size_t)(b * NV + v) * DIM)[threadIdx.x];
    float s = x.x * x.x + x.y * x.y;
#pragma unroll
    for (int off = 32; off >= 1; off >>= 1) s += __shfl_xor(s, off);
    if (threadIdx.x == 0) invnorm[i] = 1.0f / sqrtf(s + 1e-12f);
}

// ---------------- kernel 2: fused pairwise pass ----------------
// Each block owns BM=32 rows; loops over all 8192 cols in BN=128 tiles.
// 256 threads, 4x4 micro-tile: tr = tid>>5 (8 row-groups of 4), tc = tid&31,
// cols per thread: tc + n*32 (n=0..3).
__global__ __launch_bounds__(NTHR) void supcon_main(
    const float* __restrict__ feat, const float* __restrict__ labels,
    const float* __restrict__ invnorm, float* __restrict__ rowloss)
{
    __shared__ float rowT[BM][DIM];   // plain layout (reads are broadcast)
    __shared__ float colT[BN][DIM];   // XOR-swizzled float4 slots: slot = d4 ^ (c&31)
    __shared__ float labCol[BN];
    __shared__ float labRow[BM];

    const int tid  = threadIdx.x;
    const int row0 = blockIdx.x * BM;
    const int tr   = tid >> 5;   // 0..7
    const int tc   = tid & 31;   // 0..31

    // stage row tile (normalized), once
    for (int j = tid; j < BM * (DIM / 4); j += NTHR) {
        const int r = j >> 5, d4 = j & 31;
        const int i = row0 + r;
        const int b = i & (BSZ - 1), v = i >> 12;
        float4 x = reinterpret_cast<const float4*>(feat)[(size_t)(b * NV + v) * (DIM / 4) + d4];
        const float s = invnorm[i];
        x.x *= s; x.y *= s; x.z *= s; x.w *= s;
        reinterpret_cast<float4*>(&rowT[r][0])[d4] = x;
    }
    if (tid < BM) labRow[tid] = labels[(row0 + tid) & (BSZ - 1)];
    __syncthreads();

    float lr[4];
#pragma unroll
    for (int m = 0; m < 4; ++m) lr[m] = labRow[tr * 4 + m];

    float mx[4], den[4], sw[4], sws[4];
#pragma unroll
    for (int m = 0; m < 4; ++m) { mx[m] = -1e30f; den[m] = 0.f; sw[m] = 0.f; sws[m] = 0.f; }

    for (int kt = 0; kt < NTOT / BN; ++kt) {
        const int col0 = kt * BN;

        // stage column tile (normalized), swizzled
        for (int j = tid; j < BN * (DIM / 4); j += NTHR) {
            const int c = j >> 5, d4 = j & 31;
            const int k = col0 + c;
            const int b = k & (BSZ - 1), v = k >> 12;
            float4 x = reinterpret_cast<const float4*>(feat)[(size_t)(b * NV + v) * (DIM / 4) + d4];
            const float s = invnorm[k];
            x.x *= s; x.y *= s; x.z *= s; x.w *= s;
            reinterpret_cast<float4*>(&colT[c][0])[d4 ^ (c & 31)] = x;
        }
        if (tid < BN) labCol[tid] = labels[(col0 + tid) & (BSZ - 1)];
        __syncthreads();

        float4 acc[4][4];
#pragma unroll
        for (int m = 0; m < 4; ++m)
#pragma unroll
            for (int n = 0; n < 4; ++n) acc[m][n] = make_float4(0.f, 0.f, 0.f, 0.f);

#pragma unroll 4
        for (int d4 = 0; d4 < DIM / 4; ++d4) {
            float4 a[4], bb[4];
#pragma unroll
            for (int m = 0; m < 4; ++m)
                a[m] = reinterpret_cast<const float4*>(&rowT[tr * 4 + m][0])[d4];
            const int slot = d4 ^ tc;   // (tc + n*32)&31 == tc for all n
#pragma unroll
            for (int n = 0; n < 4; ++n)
                bb[n] = reinterpret_cast<const float4*>(&colT[tc + n * 32][0])[slot];
#pragma unroll
            for (int m = 0; m < 4; ++m)
#pragma unroll
                for (int n = 0; n < 4; ++n) {
                    acc[m][n].x = fmaf(a[m].x, bb[n].x, acc[m][n].x);
                    acc[m][n].y = fmaf(a[m].y, bb[n].y, acc[m][n].y);
                    acc[m][n].z = fmaf(a[m].z, bb[n].z, acc[m][n].z);
                    acc[m][n].w = fmaf(a[m].w, bb[n].w, acc[m][n].w);
                }
        }

        float lc[4];
#pragma unroll
        for (int n = 0; n < 4; ++n) lc[n] = labCol[tc + n * 32];

#pragma unroll
        for (int m = 0; m < 4; ++m) {
            const int i = row0 + tr * 4 + m;
#pragma unroll
            for (int n = 0; n < 4; ++n) {
                const int k = col0 + tc + n * 32;
                const float4 q = acc[m][n];
                const float s = (q.x + q.y + q.z + q.w) * INV_T;
                float e = __expf(s - M0);
                e = (k == i) ? 0.0f : e;       // logits_mask: diag excluded from denom
                den[m] += e;
                mx[m] = fmaxf(mx[m], s);        // max over full row incl. diag
                const float dy = lr[m] - lc[n];
                const float w = __expf(dy * dy * -0.5f);   // SIGMA=1, always in [0,1]
                sw[m] += w;                     // diag included in w sums
                sws[m] = fmaf(w, s, sws[m]);
            }
        }
        __syncthreads();
    }

    // reduce across the 32 threads sharing a tr group (lanes within a 32-lane half)
#pragma unroll
    for (int m = 0; m < 4; ++m) {
#pragma unroll
        for (int off = 16; off >= 1; off >>= 1) {
            den[m] += __shfl_xor(den[m], off);
            sw[m]  += __shfl_xor(sw[m],  off);
            sws[m] += __shfl_xor(sws[m], off);
            mx[m]   = fmaxf(mx[m], __shfl_xor(mx[m], off));
        }
    }

    if (tc == 0) {
#pragma unroll
        for (int m = 0; m < 4; ++m) {
            const int i = row0 + tr * 4 + m;
            // true denom = den * exp(M0 - mx); reference: log(denom + 1e-8)
            const float logd = logf(den[m] * __expf(M0 - mx[m]) + 1e-8f);
            const float mean = (sws[m] - (mx[m] + logd) * sw[m]) / fmaxf(sw[m], 1e-8f);
            rowloss[i] = -mean;   // TEMP/BASE_TEMP == 1
        }
    }
}

// ---------------- kernel 3: mean over rows ----------------
__global__ void reduce_mean(const float* __restrict__ rowloss, float* __restrict__ out) {
    __shared__ float part[4];
    float s = 0.f;
    for (int j = threadIdx.x; j < NTOT; j += 256) s += rowloss[j];
#pragma unroll
    for (int off = 32; off >= 1; off >>= 1) s += __shfl_xor(s, off);
    const int w = threadIdx.x >> 6;
    if ((threadIdx.x & 63) == 0) part[w] = s;
    __syncthreads();
    if (threadIdx.x == 0) out[0] = (part[0] + part[1] + part[2] + part[3]) * (1.0f / NTOT);
}

extern "C" void kernel_launch(void* const* d_in, const int* in_sizes, int n_in,
                              void* d_out, int out_size, void* d_ws, size_t ws_size,
                              hipStream_t stream) {
    const float* feat   = (const float*)d_in[0];   // (4096, 2, 128) fp32
    const float* labels = (const float*)d_in[1];   // (4096,) fp32
    float* invnorm = (float*)d_ws;                 // 8192 floats
    float* rowloss = invnorm + NTOT;               // 8192 floats
    float* out = (float*)d_out;

    norm_kernel<<<NTOT, 64, 0, stream>>>(feat, invnorm);
    supcon_main<<<NTOT / BM, NTHR, 0, stream>>>(feat, labels, invnorm, rowloss);
    reduce_mean<<<1, 256, 0, stream>>>(rowloss, out);
}

// Round 3
// 115.399 us; speedup vs baseline: 5.7194x; 5.7194x over previous
//
#include <hip/hip_runtime.h>
#include <math.h>

#define BSZ 4096
#define NTOT 8192
#define DIM 128
#define CHUNKS 16          // column chunks per 64-row stripe (512 cols each)

typedef __attribute__((ext_vector_type(8))) short short8;   // 8 bf16 = 4 VGPR
typedef __attribute__((ext_vector_type(4))) float float4v;  // MFMA acc

constexpr float INV_T = 1.0f / 0.07f;
constexpr float M0    = INV_T;                 // row max of logits = diag = 1/T
constexpr float LOG2E = 1.4426950408889634f;
constexpr float K1    = INV_T * LOG2E;         // e^(s-M0) = 2^(c*K1 - K1)
constexpr float C3    = -0.5f * LOG2E;         // w = e^(-dy^2/2) = 2^(dy^2*C3)

// ---------- kernel 1: fp32 normalize -> bf16 F[i][d], i = v*BSZ + b ----------
__global__ void norm_bf16(const float* __restrict__ feat, unsigned short* __restrict__ F) {
    const int i = blockIdx.x;
    const int b = i & (BSZ - 1), v = i >> 12;
    const int l = threadIdx.x;                 // 0..63
    const float2 x = reinterpret_cast<const float2*>(feat + (size_t)(b * 2 + v) * DIM)[l];
    float s = x.x * x.x + x.y * x.y;
#pragma unroll
    for (int off = 32; off >= 1; off >>= 1) s += __shfl_xor(s, off);
    const float inv = 1.0f / sqrtf(s + 1e-12f);
    union { float f; unsigned u; } u0, u1;
    u0.f = x.x * inv; u1.f = x.y * inv;
    const unsigned short r0 = (unsigned short)((u0.u + 0x7FFFu + ((u0.u >> 16) & 1)) >> 16);
    const unsigned short r1 = (unsigned short)((u1.u + 0x7FFFu + ((u1.u >> 16) & 1)) >> 16);
    reinterpret_cast<ushort2*>(F + (size_t)i * DIM)[l] = make_ushort2(r0, r1);
}

// ---------- kernel 2: MFMA pairwise sweep, no LDS, no barriers ----------
// grid = 128 stripes * 4 quads, 256 thr (4 waves). Wave owns 64 rows x 512 cols.
// Partials per row: den = sum_{k!=i} e^(s-M0), sw = sum w, swc = sum w*cos.
__global__ __launch_bounds__(256) void supcon_mfma(
    const unsigned short* __restrict__ F, const float* __restrict__ labels,
    float* __restrict__ part)
{
    const int tid    = threadIdx.x;
    const int wv     = tid >> 6;
    const int l      = tid & 63;
    const int stripe = blockIdx.x >> 2;        // 0..127
    const int quad   = blockIdx.x & 3;
    const int chunk  = quad * 4 + wv;          // 0..15
    const int row0   = stripe * 64;
    const int colbeg = chunk * (NTOT / CHUNKS);
    const int l15 = l & 15, lh = l >> 4;

    // A fragments: a[set][kc], row = row0 + set*16 + (l&15), k = kc*32 + (l>>4)*8 + j
    short8 a[4][4];
#pragma unroll
    for (int set = 0; set < 4; ++set) {
        const unsigned short* rp = F + (size_t)(row0 + set * 16 + l15) * DIM + lh * 8;
#pragma unroll
        for (int kc = 0; kc < 4; ++kc)
            a[set][kc] = *reinterpret_cast<const short8*>(rp + kc * 32);
    }
    // row labels for accumulator slot p = set*4 + r  (row = row0+set*16+(l>>4)*4+r)
    float lr[16];
#pragma unroll
    for (int set = 0; set < 4; ++set)
#pragma unroll
        for (int r = 0; r < 4; ++r)
            lr[set * 4 + r] = labels[(row0 + set * 16 + lh * 4 + r) & (BSZ - 1)];

    float den[16], sw[16], swc[16];
#pragma unroll
    for (int p = 0; p < 16; ++p) { den[p] = 0.f; sw[p] = 0.f; swc[p] = 0.f; }

    for (int cb = 0; cb < (NTOT / CHUNKS) / 16; ++cb) {   // 32 col-blocks of 16
        const int col0 = colbeg + cb * 16;
        const int col  = col0 + l15;
        const unsigned short* cp = F + (size_t)col * DIM + lh * 8;
        short8 bfr[4];
#pragma unroll
        for (int kc = 0; kc < 4; ++kc)
            bfr[kc] = *reinterpret_cast<const short8*>(cp + kc * 32);
        const float lc = labels[col & (BSZ - 1)];

#pragma unroll
        for (int set = 0; set < 4; ++set) {
            float4v acc = {0.f, 0.f, 0.f, 0.f};
#pragma unroll
            for (int kc = 0; kc < 4; ++kc)
                acc = __builtin_amdgcn_mfma_f32_16x16x32_bf16(a[set][kc], bfr[kc], acc, 0, 0, 0);

            if (col0 == row0 + set * 16) {      // wave-uniform: tile holds the diagonal
#pragma unroll
                for (int r = 0; r < 4; ++r) {
                    const float c = acc[r];
                    const int p = set * 4 + r;
                    float e = __builtin_amdgcn_exp2f(__builtin_fmaf(c, K1, -K1));
                    if (l15 == lh * 4 + r) e = 0.f;     // i == k
                    den[p] += e;
                    const float dy = lr[p] - lc;
                    const float w = __builtin_amdgcn_exp2f(dy * dy * C3);
                    sw[p] += w;
                    swc[p] = __builtin_fmaf(w, c, swc[p]);
                }
            } else {
#pragma unroll
                for (int r = 0; r < 4; ++r) {
                    const float c = acc[r];
                    const int p = set * 4 + r;
                    const float e = __builtin_amdgcn_exp2f(__builtin_fmaf(c, K1, -K1));
                    den[p] += e;
                    const float dy = lr[p] - lc;
                    const float w = __builtin_amdgcn_exp2f(dy * dy * C3);
                    sw[p] += w;
                    swc[p] = __builtin_fmaf(w, c, swc[p]);
                }
            }
        }
    }

    // reduce over the 16 lanes sharing each row set (cols live in l&15)
#pragma unroll
    for (int p = 0; p < 16; ++p) {
#pragma unroll
        for (int off = 1; off < 16; off <<= 1) {
            den[p] += __shfl_xor(den[p], off);
            sw[p]  += __shfl_xor(sw[p],  off);
            swc[p] += __shfl_xor(swc[p], off);
        }
    }
    if (l15 == 0) {
        float* bp = part + (size_t)(stripe * CHUNKS + chunk) * 64 * 3;
#pragma unroll
        for (int set = 0; set < 4; ++set)
#pragma unroll
            for (int r = 0; r < 4; ++r) {
                const int rl = set * 16 + lh * 4 + r;
                const int p  = set * 4 + r;
                bp[rl * 3 + 0] = den[p];
                bp[rl * 3 + 1] = sw[p];
                bp[rl * 3 + 2] = swc[p];
            }
    }
}

// ---------- kernel 3: per-row loss from chunk partials ----------
__global__ void rowloss_k(const float* __restrict__ part, float* __restrict__ rowloss) {
    const int row = blockIdx.x * 256 + threadIdx.x;
    const int stripe = row >> 6, rl = row & 63;
    float den = 0.f, sw = 0.f, swc = 0.f;
    for (int c = 0; c < CHUNKS; ++c) {
        const float* bp = part + ((size_t)(stripe * CHUNKS + c) * 64 + rl) * 3;
        den += bp[0]; sw += bp[1]; swc += bp[2];
    }
    const float logd = logf(den + 1e-8f);
    const float mean = (INV_T * swc - (M0 + logd) * sw) / fmaxf(sw, 1e-8f);
    rowloss[row] = -mean;
}

// ---------- kernel 4: mean ----------
__global__ void reduce_mean(const float* __restrict__ rowloss, float* __restrict__ out) {
    __shared__ float partlds[4];
    float s = 0.f;
    for (int j = threadIdx.x; j < NTOT; j += 256) s += rowloss[j];
#pragma unroll
    for (int off = 32; off >= 1; off >>= 1) s += __shfl_xor(s, off);
    const int w = threadIdx.x >> 6;
    if ((threadIdx.x & 63) == 0) partlds[w] = s;
    __syncthreads();
    if (threadIdx.x == 0) out[0] = (partlds[0] + partlds[1] + partlds[2] + partlds[3]) * (1.0f / NTOT);
}

extern "C" void kernel_launch(void* const* d_in, const int* in_sizes, int n_in,
                              void* d_out, int out_size, void* d_ws, size_t ws_size,
                              hipStream_t stream) {
    const float* feat   = (const float*)d_in[0];   // (4096, 2, 128) fp32
    const float* labels = (const float*)d_in[1];   // (4096,) fp32

    char* ws = (char*)d_ws;
    unsigned short* F = (unsigned short*)ws;                      // 2 MB bf16 normalized
    float* part    = (float*)(ws + (size_t)NTOT * DIM * 2);       // 128*16*64*3 f32 = 1.5 MB
    float* rowloss = part + (size_t)128 * CHUNKS * 64 * 3;        // 32 KB
    float* out = (float*)d_out;

    norm_bf16<<<NTOT, 64, 0, stream>>>(feat, F);
    supcon_mfma<<<512, 256, 0, stream>>>(F, labels, part);
    rowloss_k<<<NTOT / 256, 256, 0, stream>>>(part, rowloss);
    reduce_mean<<<1, 256, 0, stream>>>(rowloss, out);
}